// Round 4
// baseline (150.616 us; speedup 1.0000x reference)
//
#include <hip/hip_runtime.h>
#include <math.h>

#define B_  256
#define H_  256
#define C_  16384
#define S_  64
#define CS_ 32
#define K_  8
#define EPS 1e-8f
#define RET_ ((size_t)B_ * K_ * S_ * H_)   // 33,554,432 f32

typedef __attribute__((ext_vector_type(8))) short short8v;
typedef __attribute__((ext_vector_type(4))) float f32x4;

// ws layout: candbuf u64[256*2048] (4 MB) @0; mode i32 @4MB; topidx i32 after.
// d_out: [retrieved 33.5M f32][top_scores 2048 f32]

__device__ inline unsigned short f2bf(float f) {           // RTNE f32->bf16
    unsigned u = __builtin_bit_cast(unsigned, f);
    unsigned r = u + 0x7fffu + ((u >> 16) & 1u);
    return (unsigned short)(r >> 16);
}
__device__ inline unsigned ordf(float f) {                 // order-preserving f32->u32
    unsigned u = __builtin_bit_cast(unsigned, f);
    return u ^ ((u >> 31) ? 0xFFFFFFFFu : 0x80000000u);
}
__device__ inline short8v pack8(float4 a, float4 b) {
    short8v r;
    r[0] = (short)f2bf(a.x); r[1] = (short)f2bf(a.y);
    r[2] = (short)f2bf(a.z); r[3] = (short)f2bf(a.w);
    r[4] = (short)f2bf(b.x); r[5] = (short)f2bf(b.y);
    r[6] = (short)f2bf(b.z); r[7] = (short)f2bf(b.w);
    return r;
}

// Fused sim (bf16 MFMA) + per-tile per-row coarse top-8.
// Block = 64b x 64c tile; full K=256 staged once (2 barriers); 4 waves 2x2.
// key = ordf(dot*einv[c])<<32 | ~c  (higher = better score, then lower idx).
#define LSTR 264   // 256 + 8 pad: 528B row stride -> 2-way (free) ds_read_b128
__global__ __launch_bounds__(256) void simsel_kernel(const float* __restrict__ q,
                                                     const float* __restrict__ e,
                                                     unsigned long long* __restrict__ candbuf) {
    __shared__ union {
        struct { unsigned short Qs[64 * LSTR]; unsigned short Es[64 * LSTR]; } st;
        float tile[64 * 65];   // f32 sim tile, stride 65 -> conflict-free col scan
    } sm;
    __shared__ float einv_s[64];
    const int t = threadIdx.x, lane = t & 63, wv = t >> 6;
    const int wm = wv >> 1, wn = wv & 1;
    // XCD swizzle: the 4 b-blocks of one c-tile are dispatch-consecutive mod 8
    // -> same XCD L2 (e-tile fetched once from HBM).
    const int bid = blockIdx.x;
    const int ct = (bid & 7) * 32 + ((bid >> 3) >> 2);
    const int bt = (bid >> 3) & 3;
    const int c0 = ct * 64, b0 = bt * 64;
    const int r = t >> 2, g = t & 3;              // staging: row, quarter
    const float4* q4 = (const float4*)q;
    const float4* e4 = (const float4*)e;

    // ---- stage full K=256 (f32 -> bf16), accumulate e row sumsq ----
    float esq = 0.f;
    #pragma unroll
    for (int u = 0; u < 16; u += 2) {
        float4 a0 = q4[(size_t)(b0 + r) * 64 + g * 16 + u];
        float4 a1 = q4[(size_t)(b0 + r) * 64 + g * 16 + u + 1];
        *(short8v*)&sm.st.Qs[r * LSTR + g * 64 + u * 4] = pack8(a0, a1);
        float4 e0 = e4[(size_t)(c0 + r) * 64 + g * 16 + u];
        float4 e1 = e4[(size_t)(c0 + r) * 64 + g * 16 + u + 1];
        esq += e0.x * e0.x + e0.y * e0.y + e0.z * e0.z + e0.w * e0.w
             + e1.x * e1.x + e1.y * e1.y + e1.z * e1.z + e1.w * e1.w;
        *(short8v*)&sm.st.Es[r * LSTR + g * 64 + u * 4] = pack8(e0, e1);
    }
    esq += __shfl_xor(esq, 1);
    esq += __shfl_xor(esq, 2);                    // 4-lane group = one row
    if (g == 0) einv_s[r] = 1.0f / fmaxf(sqrtf(esq), EPS);
    __syncthreads();

    // ---- MFMA: wave = 32x32, 2x2 frags of 16x16x32, 8 k-steps ----
    f32x4 acc[2][2];
    #pragma unroll
    for (int i = 0; i < 2; ++i)
        #pragma unroll
        for (int j = 0; j < 2; ++j) acc[i][j] = (f32x4){0.f, 0.f, 0.f, 0.f};
    #pragma unroll
    for (int hc = 0; hc < 8; ++hc) {
        short8v afr[2], bfr[2];
        #pragma unroll
        for (int mi = 0; mi < 2; ++mi)
            afr[mi] = *(short8v*)&sm.st.Qs[(wm * 32 + mi * 16 + (lane & 15)) * LSTR
                                           + hc * 32 + (lane >> 4) * 8];
        #pragma unroll
        for (int ni = 0; ni < 2; ++ni)
            bfr[ni] = *(short8v*)&sm.st.Es[(wn * 32 + ni * 16 + (lane & 15)) * LSTR
                                           + hc * 32 + (lane >> 4) * 8];
        #pragma unroll
        for (int mi = 0; mi < 2; ++mi)
            #pragma unroll
            for (int ni = 0; ni < 2; ++ni)
                acc[mi][ni] = __builtin_amdgcn_mfma_f32_16x16x32_bf16(
                    afr[mi], bfr[ni], acc[mi][ni], 0, 0, 0);
    }
    __syncthreads();   // all LDS reads done before tile overwrites the union

    // ---- dump scaled sims to LDS tile ----
    #pragma unroll
    for (int mi = 0; mi < 2; ++mi)
        #pragma unroll
        for (int j = 0; j < 4; ++j) {
            int row = wm * 32 + mi * 16 + (lane >> 4) * 4 + j;
            #pragma unroll
            for (int ni = 0; ni < 2; ++ni) {
                int col = wn * 32 + ni * 16 + (lane & 15);
                sm.tile[row * 65 + col] = acc[mi][ni][j] * einv_s[col];
            }
        }
    __syncthreads();

    // ---- wave 0: per-row top-8 over the 64-col tile (u64 keys) ----
    if (t < 64) {
        unsigned long long best[8];
        #pragma unroll
        for (int k = 0; k < 8; ++k) best[k] = 0ull;   // < any real key
        for (int c = 0; c < 64; ++c) {
            float v = sm.tile[t * 65 + c];
            unsigned long long key = ((unsigned long long)ordf(v) << 32)
                                   | (unsigned)(0xFFFFFFFFu - (unsigned)(c0 + c));
            if (key > best[7]) {
                best[7] = key;
                #pragma unroll
                for (int k = 7; k > 0; --k)
                    if (best[k] > best[k - 1]) {
                        unsigned long long tmp = best[k];
                        best[k] = best[k - 1]; best[k - 1] = tmp;
                    }
            }
        }
        #pragma unroll
        for (int k = 0; k < 8; ++k)
            candbuf[(size_t)(b0 + t) * 2048 + ct * 8 + k] = best[k];
    }
}

// Blocks 0..255: merge 2048 candidates -> bitonic sort -> coarse top-32 ->
// exact f32 rescore -> final top-8 (JAX tie-break). Block 256: detect mode.
__global__ __launch_bounds__(256) void merge_kernel(const float* __restrict__ q,
                                                    const float* __restrict__ e,
                                                    const unsigned long long* __restrict__ candbuf,
                                                    const unsigned* __restrict__ icw,
                                                    int* __restrict__ mode,
                                                    float* __restrict__ out_scores,
                                                    int* __restrict__ top_idx) {
    const int t = threadIdx.x, b = blockIdx.x;
    if (b == 256) {     // is_compressed: byte-bool (1) or int32 (0)?
        __shared__ int f;
        if (t == 0) f = 0;
        __syncthreads();
        int any = 0;
        for (int i = t; i < 4096; i += 256)
            if (icw[i] & 0xFFFFFF00u) any = 1;
        if (any) atomicOr(&f, 1);
        __syncthreads();
        if (t == 0) *mode = f;
        return;
    }

    __shared__ unsigned long long keys[2048];
    __shared__ float rs[32];
    __shared__ int   ri[32];
    const unsigned long long* row = candbuf + (size_t)b * 2048;
    #pragma unroll
    for (int k = 0; k < 8; ++k) keys[t * 8 + k] = row[t * 8 + k];
    __syncthreads();

    // bitonic sort ascending; top-32 ends at keys[2016..2047]
    for (int k = 2; k <= 2048; k <<= 1) {
        for (int j = k >> 1; j > 0; j >>= 1) {
            #pragma unroll
            for (int base = 0; base < 2048; base += 256) {
                int i = base + t, l = i ^ j;
                if (l > i) {
                    unsigned long long a = keys[i], bb = keys[l];
                    bool up = ((i & k) == 0);
                    if ((a > bb) == up) { keys[i] = bb; keys[l] = a; }
                }
            }
            __syncthreads();
        }
    }

    // exact f32 rescore of top-32; 4 waves x 8 candidates
    const int wv = t >> 6, lane = t & 63;
    float4 qv = ((const float4*)q)[(size_t)b * 64 + lane];
    float qsq = qv.x * qv.x + qv.y * qv.y + qv.z * qv.z + qv.w * qv.w;
    #pragma unroll
    for (int d = 1; d < 64; d <<= 1) qsq += __shfl_xor(qsq, d);
    float qi = 1.0f / fmaxf(sqrtf(qsq), EPS);

    for (int m = wv; m < 32; m += 4) {
        unsigned long long key = keys[2047 - m];
        int idx = (int)(0xFFFFFFFFu - (unsigned)(key & 0xFFFFFFFFull));
        float4 ev = ((const float4*)e)[(size_t)idx * 64 + lane];
        float dot = qv.x * ev.x + qv.y * ev.y + qv.z * ev.z + qv.w * ev.w;
        float ss  = ev.x * ev.x + ev.y * ev.y + ev.z * ev.z + ev.w * ev.w;
        #pragma unroll
        for (int d = 1; d < 64; d <<= 1) {
            dot += __shfl_xor(dot, d);
            ss  += __shfl_xor(ss, d);
        }
        if (lane == 0) {
            rs[m] = dot * qi * (1.0f / fmaxf(sqrtf(ss), EPS));
            ri[m] = idx;
        }
    }
    __syncthreads();

    if (t < 64) {       // final top-8 of 32 (score desc, idx asc)
        float val; int idx, slot;
        if (t < 32) { val = rs[t]; idx = ri[t]; slot = t; }
        else        { val = -INFINITY; idx = 0x7fffffff; slot = -1; }
        for (int p = 0; p < 8; ++p) {
            float bs = val; int bi = idx, bsl = slot;
            #pragma unroll
            for (int d = 1; d < 64; d <<= 1) {
                float os = __shfl_xor(bs, d);
                int   oi = __shfl_xor(bi, d);
                int   osl = __shfl_xor(bsl, d);
                if (os > bs || (os == bs && oi < bi)) { bs = os; bi = oi; bsl = osl; }
            }
            if (t == 0) { out_scores[b * K_ + p] = bs; top_idx[b * K_ + p] = bi; }
            if (slot == bsl) val = -INFINITY;
        }
    }
}

// One block per (b,j): contiguous 64KB read + 64KB write, nontemporal.
__global__ __launch_bounds__(256) void gather_kernel(const float* __restrict__ epi,
                                                     const float* __restrict__ comp,
                                                     const void* __restrict__ icp,
                                                     const int* __restrict__ top_idx,
                                                     const int* __restrict__ mode,
                                                     float* __restrict__ out) {
    const int bj = blockIdx.x;
    const int c = top_idx[bj];
    const int m = *mode;
    const int flag = m ? (((const unsigned char*)icp)[c] != 0)
                       : (((const int*)icp)[c] != 0);
    f32x4* o4 = (f32x4*)out + (size_t)bj * 4096;
    if (!flag) {
        const f32x4* s4 = (const f32x4*)epi + (size_t)c * 4096;
        #pragma unroll 4
        for (int i = threadIdx.x; i < 4096; i += 256)
            __builtin_nontemporal_store(__builtin_nontemporal_load(s4 + i), o4 + i);
    } else {
        const f32x4* s4 = (const f32x4*)comp + (size_t)c * 2048;
        #pragma unroll 4
        for (int i = threadIdx.x; i < 2048; i += 256)
            __builtin_nontemporal_store(__builtin_nontemporal_load(s4 + i), o4 + i);
        const f32x4 z = (f32x4){0.f, 0.f, 0.f, 0.f};
        #pragma unroll 4
        for (int i = 2048 + threadIdx.x; i < 4096; i += 256)
            __builtin_nontemporal_store(z, o4 + i);
    }
}

extern "C" void kernel_launch(void* const* d_in, const int* in_sizes, int n_in,
                              void* d_out, int out_size, void* d_ws, size_t ws_size,
                              hipStream_t stream) {
    const float* query = (const float*)d_in[0];
    const float* emb   = (const float*)d_in[1];
    const float* epi   = (const float*)d_in[2];
    const float* comp  = (const float*)d_in[3];
    const void*  icp   = d_in[4];
    float* out = (float*)d_out;

    unsigned long long* candbuf = (unsigned long long*)d_ws;          // 4 MB
    int* mode   = (int*)((char*)d_ws + (4u << 20));
    int* topidx = mode + 1;
    float* out_scores = out + RET_;

    simsel_kernel<<<1024, 256, 0, stream>>>(query, emb, candbuf);
    merge_kernel<<<257, 256, 0, stream>>>(query, emb, candbuf, (const unsigned*)icp,
                                          mode, out_scores, topidx);
    gather_kernel<<<B_ * K_, 256, 0, stream>>>(epi, comp, icp, topidx, mode, out);
}

// Round 5
// 132.255 us; speedup vs baseline: 1.1388x; 1.1388x over previous
//
#include <hip/hip_runtime.h>
#include <math.h>

#define B_  256
#define H_  256
#define C_  16384
#define S_  64
#define CS_ 32
#define K_  8
#define EPS 1e-8f
#define RET_ ((size_t)B_ * K_ * S_ * H_)   // 33,554,432 f32

typedef __attribute__((ext_vector_type(8))) short short8v;
typedef __attribute__((ext_vector_type(4))) float f32x4;

// ws: candbuf u64[256*2048] (4 MB) @0; mode i32 @4MB.
// d_out: [retrieved 33.5M f32][top_scores 2048 f32]; no scratch in d_out.

__device__ inline unsigned short f2bf(float f) {           // RTNE f32->bf16
    unsigned u = __builtin_bit_cast(unsigned, f);
    unsigned r = u + 0x7fffu + ((u >> 16) & 1u);
    return (unsigned short)(r >> 16);
}
__device__ inline unsigned ordf(float f) {                 // order-preserving f32->u32
    unsigned u = __builtin_bit_cast(unsigned, f);
    return u ^ ((u >> 31) ? 0xFFFFFFFFu : 0x80000000u);
}
__device__ inline short8v pack8(float4 a, float4 b) {
    short8v r;
    r[0] = (short)f2bf(a.x); r[1] = (short)f2bf(a.y);
    r[2] = (short)f2bf(a.z); r[3] = (short)f2bf(a.w);
    r[4] = (short)f2bf(b.x); r[5] = (short)f2bf(b.y);
    r[6] = (short)f2bf(b.z); r[7] = (short)f2bf(b.w);
    return r;
}
__device__ inline void ce(unsigned long long& a, unsigned long long& b) {  // desc
    unsigned long long lo = a < b ? a : b;
    a = a < b ? b : a;
    b = lo;
}
// best: sorted desc. Merge with xor-partner's sorted-desc list -> top-8 of 16.
__device__ inline void merge_shfl(unsigned long long best[8], int xorlane) {
    unsigned long long m[8];
    #pragma unroll
    for (int i = 0; i < 8; ++i) {
        unsigned long long p = __shfl_xor(best[7 - i], xorlane);
        m[i] = best[i] > p ? best[i] : p;      // bitonic first step: top-8 set
    }
    // m is bitonic; sort desc with 3-stage network
    ce(m[0], m[4]); ce(m[1], m[5]); ce(m[2], m[6]); ce(m[3], m[7]);
    ce(m[0], m[2]); ce(m[1], m[3]); ce(m[4], m[6]); ce(m[5], m[7]);
    ce(m[0], m[1]); ce(m[2], m[3]); ce(m[4], m[5]); ce(m[6], m[7]);
    #pragma unroll
    for (int i = 0; i < 8; ++i) best[i] = m[i];
}

// Fused bf16-MFMA sim + per-tile per-row top-8 (all-thread parallel).
// Block = 64b x 64c; K chunked by 32 (8 phases, LSTR=40 -> 10 KB staging LDS).
// Block 1024: detect is_compressed storage width.
#define LSTR 40
__global__ __launch_bounds__(256) void simsel_kernel(const float* __restrict__ q,
                                                     const float* __restrict__ e,
                                                     const unsigned* __restrict__ icw,
                                                     unsigned long long* __restrict__ candbuf,
                                                     int* __restrict__ mode) {
    const int t = threadIdx.x;
    if (blockIdx.x == 1024) {   // byte-bool (1) vs int32 (0)
        __shared__ int f;
        if (t == 0) f = 0;
        __syncthreads();
        int any = 0;
        for (int i = t; i < 4096; i += 256)
            if (icw[i] & 0xFFFFFF00u) any = 1;
        if (any) atomicOr(&f, 1);
        __syncthreads();
        if (t == 0) *mode = f;
        return;
    }

    __shared__ union {
        struct { unsigned short Qs[64 * LSTR]; unsigned short Es[64 * LSTR]; } st;
        float tile[64 * 65];   // stride-65 f32 sim tile (2-way max on reads)
    } sm;
    __shared__ float einv_s[64];
    const int lane = t & 63, wv = t >> 6;
    const int wm = wv >> 1, wn = wv & 1;
    // XCD swizzle: bids {x, x+8, x+16, x+24} share one c-tile on one XCD.
    const int bid = blockIdx.x;
    const int ct = (bid & 7) * 32 + (bid >> 5);
    const int bt = (bid >> 3) & 3;
    const int c0 = ct * 64, b0 = bt * 64;
    const int r = t >> 2, g = t & 3;              // staging: row, quarter
    const float4* q4 = (const float4*)q;
    const float4* e4 = (const float4*)e;

    float esq = 0.f;
    f32x4 acc[2][2];
    #pragma unroll
    for (int i = 0; i < 2; ++i)
        #pragma unroll
        for (int j = 0; j < 2; ++j) acc[i][j] = (f32x4){0.f, 0.f, 0.f, 0.f};

    for (int hc = 0; hc < 8; ++hc) {
        __syncthreads();
        float4 a0 = q4[(size_t)(b0 + r) * 64 + hc * 8 + g * 2];
        float4 a1 = q4[(size_t)(b0 + r) * 64 + hc * 8 + g * 2 + 1];
        float4 e0 = e4[(size_t)(c0 + r) * 64 + hc * 8 + g * 2];
        float4 e1 = e4[(size_t)(c0 + r) * 64 + hc * 8 + g * 2 + 1];
        esq += e0.x * e0.x + e0.y * e0.y + e0.z * e0.z + e0.w * e0.w
             + e1.x * e1.x + e1.y * e1.y + e1.z * e1.z + e1.w * e1.w;
        *(short8v*)&sm.st.Qs[r * LSTR + g * 8] = pack8(a0, a1);
        *(short8v*)&sm.st.Es[r * LSTR + g * 8] = pack8(e0, e1);
        __syncthreads();

        short8v afr[2], bfr[2];
        #pragma unroll
        for (int mi = 0; mi < 2; ++mi)
            afr[mi] = *(short8v*)&sm.st.Qs[(wm * 32 + mi * 16 + (lane & 15)) * LSTR + (lane >> 4) * 8];
        #pragma unroll
        for (int ni = 0; ni < 2; ++ni)
            bfr[ni] = *(short8v*)&sm.st.Es[(wn * 32 + ni * 16 + (lane & 15)) * LSTR + (lane >> 4) * 8];
        #pragma unroll
        for (int mi = 0; mi < 2; ++mi)
            #pragma unroll
            for (int ni = 0; ni < 2; ++ni)
                acc[mi][ni] = __builtin_amdgcn_mfma_f32_16x16x32_bf16(
                    afr[mi], bfr[ni], acc[mi][ni], 0, 0, 0);
    }

    esq += __shfl_xor(esq, 1);
    esq += __shfl_xor(esq, 2);                    // 4-lane group = one e row
    if (g == 0) einv_s[r] = 1.0f / fmaxf(sqrtf(esq), EPS);
    __syncthreads();   // staging reads done (waitcnt before barrier) + einv vis

    // dump scaled sims over the staging region
    #pragma unroll
    for (int mi = 0; mi < 2; ++mi)
        #pragma unroll
        for (int j = 0; j < 4; ++j) {
            int row = wm * 32 + mi * 16 + (lane >> 4) * 4 + j;
            #pragma unroll
            for (int ni = 0; ni < 2; ++ni) {
                int col = wn * 32 + ni * 16 + (lane & 15);
                sm.tile[row * 65 + col] = acc[mi][ni][j] * einv_s[col];
            }
        }
    __syncthreads();

    // thread (r,g): top-8 of its 16 cols, then 2 shfl-merge rounds -> top-8 of 64
    unsigned long long best[8];
    #pragma unroll
    for (int k = 0; k < 8; ++k) best[k] = 0ull;
    for (int i = 0; i < 16; ++i) {
        int c = g * 16 + i;
        float v = sm.tile[r * 65 + c];
        unsigned long long key = ((unsigned long long)ordf(v) << 32)
                               | (unsigned)(0xFFFFFFFFu - (unsigned)(c0 + c));
        if (key > best[7]) {
            best[7] = key;
            #pragma unroll
            for (int k = 7; k > 0; --k)
                if (best[k] > best[k - 1]) {
                    unsigned long long tmp = best[k];
                    best[k] = best[k - 1]; best[k - 1] = tmp;
                }
        }
    }
    merge_shfl(best, 1);   // quarters 0<->1, 2<->3
    merge_shfl(best, 2);   // -> exact per-row top-8 (all 4 threads agree)
    if (g == 0) {
        #pragma unroll
        for (int k = 0; k < 8; ++k)
            candbuf[(size_t)(b0 + r) * 2048 + ct * 8 + k] = best[k];
    }
}

// One block per row b: bitonic-sort 2048 candidates -> coarse top-32 ->
// exact f32 rescore -> final top-8 (JAX tie-break) -> gather 8 x 64KB.
__global__ __launch_bounds__(256) void merge_gather_kernel(
        const float* __restrict__ q, const float* __restrict__ e,
        const unsigned long long* __restrict__ candbuf,
        const void* __restrict__ icp, const int* __restrict__ mode,
        const float* __restrict__ epi, const float* __restrict__ comp,
        float* __restrict__ out, float* __restrict__ out_scores) {
    __shared__ unsigned long long keys[2048];
    __shared__ float rs[32];
    __shared__ int   ri[32];
    __shared__ int   top_lds[8];
    const int t = threadIdx.x, b = blockIdx.x;

    const unsigned long long* row = candbuf + (size_t)b * 2048;
    #pragma unroll
    for (int k = 0; k < 8; ++k) keys[t * 8 + k] = row[t * 8 + k];
    __syncthreads();

    for (int k = 2; k <= 2048; k <<= 1) {          // ascending; top at the end
        for (int j = k >> 1; j > 0; j >>= 1) {
            #pragma unroll
            for (int base = 0; base < 2048; base += 256) {
                int i = base + t, l = i ^ j;
                if (l > i) {
                    unsigned long long a = keys[i], bb = keys[l];
                    bool up = ((i & k) == 0);
                    if ((a > bb) == up) { keys[i] = bb; keys[l] = a; }
                }
            }
            __syncthreads();
        }
    }

    // exact f32 rescore of coarse top-32; 4 waves x 8 candidates
    const int wv = t >> 6, lane = t & 63;
    float4 qv = ((const float4*)q)[(size_t)b * 64 + lane];
    float qsq = qv.x * qv.x + qv.y * qv.y + qv.z * qv.z + qv.w * qv.w;
    #pragma unroll
    for (int d = 1; d < 64; d <<= 1) qsq += __shfl_xor(qsq, d);
    float qi = 1.0f / fmaxf(sqrtf(qsq), EPS);

    for (int m = wv; m < 32; m += 4) {
        unsigned long long key = keys[2047 - m];
        int idx = (int)(0xFFFFFFFFu - (unsigned)(key & 0xFFFFFFFFull));
        float4 ev = ((const float4*)e)[(size_t)idx * 64 + lane];
        float dot = qv.x * ev.x + qv.y * ev.y + qv.z * ev.z + qv.w * ev.w;
        float ss  = ev.x * ev.x + ev.y * ev.y + ev.z * ev.z + ev.w * ev.w;
        #pragma unroll
        for (int d = 1; d < 64; d <<= 1) {
            dot += __shfl_xor(dot, d);
            ss  += __shfl_xor(ss, d);
        }
        if (lane == 0) {
            rs[m] = dot * qi * (1.0f / fmaxf(sqrtf(ss), EPS));
            ri[m] = idx;
        }
    }
    __syncthreads();

    if (t < 64) {       // final top-8 of 32 (score desc, idx asc)
        float val; int idx, slot;
        if (t < 32) { val = rs[t]; idx = ri[t]; slot = t; }
        else        { val = -INFINITY; idx = 0x7fffffff; slot = -1; }
        for (int p = 0; p < 8; ++p) {
            float bs = val; int bi = idx, bsl = slot;
            #pragma unroll
            for (int d = 1; d < 64; d <<= 1) {
                float os = __shfl_xor(bs, d);
                int   oi = __shfl_xor(bi, d);
                int   osl = __shfl_xor(bsl, d);
                if (os > bs || (os == bs && oi < bi)) { bs = os; bi = oi; bsl = osl; }
            }
            if (t == 0) { out_scores[b * K_ + p] = bs; top_lds[p] = bi; }
            if (slot == bsl) val = -INFINITY;
        }
    }
    __syncthreads();

    // gather: 8 x (64KB read + 64KB write), nontemporal streaming
    const int m_ = *mode;
    for (int j = 0; j < K_; ++j) {
        const int c = top_lds[j];
        const int flag = m_ ? (((const unsigned char*)icp)[c] != 0)
                            : (((const int*)icp)[c] != 0);
        f32x4* o4 = (f32x4*)out + ((size_t)b * K_ + j) * 4096;
        if (!flag) {
            const f32x4* s4 = (const f32x4*)epi + (size_t)c * 4096;
            #pragma unroll 4
            for (int i = t; i < 4096; i += 256)
                __builtin_nontemporal_store(__builtin_nontemporal_load(s4 + i), o4 + i);
        } else {
            const f32x4* s4 = (const f32x4*)comp + (size_t)c * 2048;
            #pragma unroll 4
            for (int i = t; i < 2048; i += 256)
                __builtin_nontemporal_store(__builtin_nontemporal_load(s4 + i), o4 + i);
            const f32x4 z = (f32x4){0.f, 0.f, 0.f, 0.f};
            #pragma unroll 4
            for (int i = 2048 + t; i < 4096; i += 256)
                __builtin_nontemporal_store(z, o4 + i);
        }
    }
}

extern "C" void kernel_launch(void* const* d_in, const int* in_sizes, int n_in,
                              void* d_out, int out_size, void* d_ws, size_t ws_size,
                              hipStream_t stream) {
    const float* query = (const float*)d_in[0];
    const float* emb   = (const float*)d_in[1];
    const float* epi   = (const float*)d_in[2];
    const float* comp  = (const float*)d_in[3];
    const void*  icp   = d_in[4];
    float* out = (float*)d_out;

    unsigned long long* candbuf = (unsigned long long*)d_ws;          // 4 MB
    int* mode = (int*)((char*)d_ws + (4u << 20));
    float* out_scores = out + RET_;

    simsel_kernel<<<1025, 256, 0, stream>>>(query, emb, (const unsigned*)icp,
                                            candbuf, mode);
    merge_gather_kernel<<<B_, 256, 0, stream>>>(query, emb, candbuf, icp, mode,
                                                epi, comp, out, out_scores);
}